// Round 1
// baseline (170.224 us; speedup 1.0000x reference)
//
#include <hip/hip_runtime.h>

#define B_  32
#define CL_ 1024
#define QL_ 512
#define D_  256
#define BM  32

typedef _Float16 f16;
typedef __attribute__((ext_vector_type(2))) _Float16 f16x2;
typedef __attribute__((ext_vector_type(4))) _Float16 f16x4;
typedef __attribute__((ext_vector_type(8))) _Float16 f16x8;
typedef __attribute__((ext_vector_type(4))) float    f32x4;

// ---------------- K0a: q -> f16 cast + sqv[b,j] = q . w_q ----------------
__global__ __launch_bounds__(256) void k0a_qcast(const float* __restrict__ q,
                                                 const float* __restrict__ w_q,
                                                 f16* __restrict__ q_h,
                                                 float* __restrict__ sqv) {
  int gw   = (blockIdx.x * 256 + threadIdx.x) >> 6;   // one wave per q row
  int lane = threadIdx.x & 63;
  const float* row = q + (size_t)gw * D_ + lane * 4;
  f32x4 v  = *(const f32x4*)row;
  f32x4 wv = *(const f32x4*)(w_q + lane * 4);
  f16x4 h;
  h[0] = (f16)v[0]; h[1] = (f16)v[1]; h[2] = (f16)v[2]; h[3] = (f16)v[3];
  *(f16x4*)(q_h + (size_t)gw * D_ + lane * 4) = h;
  float dot = v[0]*wv[0] + v[1]*wv[1] + v[2]*wv[2] + v[3]*wv[3];
  #pragma unroll
  for (int m = 1; m < 64; m <<= 1) dot += __shfl_xor(dot, m, 64);
  if (lane == 0) sqv[gw] = dot;
}

// ---------------- K0b: qT_h[b][d][j] = q_h[b][j][d] (L1-tiled gather) ----
__global__ __launch_bounds__(256) void k0b_qtrans(const f16* __restrict__ q_h,
                                                  f16* __restrict__ qT_h) {
  int b  = blockIdx.z;
  int d0 = blockIdx.y * 64, j0 = blockIdx.x * 64;
  const f16* qb = q_h + (size_t)b * QL_ * D_;
  f16*       ob = qT_h + (size_t)b * D_ * QL_;
  #pragma unroll
  for (int s = 0; s < 8; ++s) {
    int e  = threadIdx.x + 256 * s;     // 0..2047 (64 d x 32 j-pairs)
    int d  = e >> 5;
    int j2 = (e & 31) * 2;
    f16x2 p;
    p[0] = qb[(size_t)(j0 + j2    ) * D_ + d0 + d];
    p[1] = qb[(size_t)(j0 + j2 + 1) * D_ + d0 + d];
    *(f16x2*)(ob + (size_t)(d0 + d) * QL_ + j0 + j2) = p;
  }
}

// ---------------- K1: scores + softmax + PV + epilogue -------------------
// block: (i-tile of 32 rows, batch b), 512 threads = 8 waves.
// LDS union (63360 B):
//  phase A: cw_t[32][264] f16 @0 (16896) | qj_t[512][40] f16 @16896 (40960)
//  phase C: P_t[32][520] f16 @0 (33280)  | qT_t[256][40] f16 @33280 (20480)
//  smalls @57856: sqv_l[512] wcq_l[256] wc_l[256] scv_l[32] red[8][32] mf[32] lf[32]
__global__ __launch_bounds__(512) void k1_attn(
    const float* __restrict__ c, const f16* __restrict__ q_h,
    const f16* __restrict__ qT_h, const float* __restrict__ sqv,
    const float* __restrict__ w_c, const float* __restrict__ w_cq,
    float* __restrict__ out, float* __restrict__ mrow)
{
  __shared__ alignas(16) char smem[63360];
  f16 (*cw_t)[264] = (f16 (*)[264])(smem);
  f16 (*qj_t)[40]  = (f16 (*)[40])(smem + 16896);
  f16 (*P_t)[520]  = (f16 (*)[520])(smem);
  f16 (*qT_t)[40]  = (f16 (*)[40])(smem + 33280);
  float* sqv_l = (float*)(smem + 57856);
  float* wcq_l = (float*)(smem + 59904);
  float* wc_l  = (float*)(smem + 60928);
  float* scv_l = (float*)(smem + 61952);
  float (*red)[BM] = (float (*)[BM])(smem + 62080);
  float* mf = (float*)(smem + 63104);
  float* lf = (float*)(smem + 63232);

  const int tid = threadIdx.x;
  const int w = tid >> 6, l = tid & 63, g = l >> 4, l15 = l & 15;
  const int b = blockIdx.y, i0 = blockIdx.x * BM;

  if (tid < 256) { wcq_l[tid] = w_cq[tid]; wc_l[tid] = w_c[tid]; }
  sqv_l[tid] = sqv[b * QL_ + tid];
  __syncthreads();

  // stage cw_t = f16(c * w_cq); scv = c . w_c (f32)
  {
    int r = tid >> 4, seg = tid & 15;
    const float* crow = c + (size_t)(b * CL_ + i0 + r) * D_;
    float dot = 0.f;
    #pragma unroll
    for (int u = 0; u < 4; ++u) {
      int d = seg * 16 + u * 4;
      f32x4 v  = *(const f32x4*)(crow + d);
      f32x4 wv = *(const f32x4*)(wcq_l + d);
      f32x4 w2 = *(const f32x4*)(wc_l + d);
      f16x4 h;
      h[0] = (f16)(v[0]*wv[0]); h[1] = (f16)(v[1]*wv[1]);
      h[2] = (f16)(v[2]*wv[2]); h[3] = (f16)(v[3]*wv[3]);
      *(f16x4*)(&cw_t[r][d]) = h;
      dot += v[0]*w2[0] + v[1]*w2[1] + v[2]*w2[2] + v[3]*w2[3];
    }
    dot += __shfl_xor(dot, 1, 64); dot += __shfl_xor(dot, 2, 64);
    dot += __shfl_xor(dot, 4, 64); dot += __shfl_xor(dot, 8, 64);
    if (seg == 0) scv_l[r] = dot;
  }

  // ---- Phase A: U = (c*w_cq) @ q^T, wave w owns j-slice [64w,64w+64) ----
  f32x4 acc[2][4];
  #pragma unroll
  for (int fi = 0; fi < 2; ++fi)
    #pragma unroll
    for (int fj = 0; fj < 4; ++fj)
      acc[fi][fj] = (f32x4){0.f,0.f,0.f,0.f};

  const f16* qhb = q_h + (size_t)b * QL_ * D_;
  for (int dk = 0; dk < 8; ++dk) {
    #pragma unroll
    for (int s = 0; s < 4; ++s) {
      int cidx = tid + 512 * s;          // 512 rows x 4 16B-chunks
      int row = cidx >> 2, co = cidx & 3;
      *(f16x8*)(&qj_t[row][co * 8]) =
          *(const f16x8*)(qhb + (size_t)row * D_ + dk * 32 + co * 8);
    }
    __syncthreads();
    f16x8 a0 = *(const f16x8*)(&cw_t[l15     ][dk * 32 + 8 * g]);
    f16x8 a1 = *(const f16x8*)(&cw_t[16 + l15][dk * 32 + 8 * g]);
    #pragma unroll
    for (int fj = 0; fj < 4; ++fj) {
      f16x8 bf = *(const f16x8*)(&qj_t[w * 64 + 16 * fj + l15][8 * g]);
      acc[0][fj] = __builtin_amdgcn_mfma_f32_16x16x32_f16(a0, bf, acc[0][fj], 0, 0, 0);
      acc[1][fj] = __builtin_amdgcn_mfma_f32_16x16x32_f16(a1, bf, acc[1][fj], 0, 0, 0);
    }
    __syncthreads();
  }

  // ---- Phase B: softmax over j (full 512 per row) ----
  float rmax[2][4];
  #pragma unroll
  for (int fi = 0; fi < 2; ++fi) {
    #pragma unroll
    for (int r = 0; r < 4; ++r) {
      float mx = -1e30f;
      #pragma unroll
      for (int fj = 0; fj < 4; ++fj) {
        float v = acc[fi][fj][r] + sqv_l[w * 64 + 16 * fj + l15];
        acc[fi][fj][r] = v;
        mx = fmaxf(mx, v);
      }
      mx = fmaxf(mx, __shfl_xor(mx, 1, 64));
      mx = fmaxf(mx, __shfl_xor(mx, 2, 64));
      mx = fmaxf(mx, __shfl_xor(mx, 4, 64));
      mx = fmaxf(mx, __shfl_xor(mx, 8, 64));
      rmax[fi][r] = mx;
    }
  }
  if (l15 == 0) {
    #pragma unroll
    for (int fi = 0; fi < 2; ++fi)
      #pragma unroll
      for (int r = 0; r < 4; ++r)
        red[w][16 * fi + 4 * g + r] = rmax[fi][r];
  }
  __syncthreads();
  if (tid < BM) {
    float m = red[0][tid];
    #pragma unroll
    for (int w2 = 1; w2 < 8; ++w2) m = fmaxf(m, red[w2][tid]);
    mf[tid] = m;
    mrow[b * CL_ + i0 + tid] = m + scv_l[tid];   // + scv for bvec path
  }
  __syncthreads();

  float rsum[2][4];
  #pragma unroll
  for (int fi = 0; fi < 2; ++fi) {
    #pragma unroll
    for (int r = 0; r < 4; ++r) {
      int il = 16 * fi + 4 * g + r;
      float mv = mf[il];
      float s = 0.f;
      #pragma unroll
      for (int fj = 0; fj < 4; ++fj) {
        float p = __expf(acc[fi][fj][r] - mv);
        s += p;
        P_t[il][w * 64 + 16 * fj + l15] = (f16)p;   // overlaps dead cw/qj regions
      }
      s += __shfl_xor(s, 1, 64); s += __shfl_xor(s, 2, 64);
      s += __shfl_xor(s, 4, 64); s += __shfl_xor(s, 8, 64);
      rsum[fi][r] = s;
    }
  }
  if (l15 == 0) {
    #pragma unroll
    for (int fi = 0; fi < 2; ++fi)
      #pragma unroll
      for (int r = 0; r < 4; ++r)
        red[w][16 * fi + 4 * g + r] = rsum[fi][r];
  }
  __syncthreads();
  if (tid < BM) {
    float s = 0.f;
    #pragma unroll
    for (int w2 = 0; w2 < 8; ++w2) s += red[w2][tid];
    lf[tid] = 1.0f / s;
  }
  __syncthreads();

  // ---- Phase C: O = P @ q, wave w owns d-slice [32w,32w+32) ----
  f32x4 o[2][2];
  o[0][0] = (f32x4){0.f,0.f,0.f,0.f}; o[0][1] = o[0][0];
  o[1][0] = o[0][0];                  o[1][1] = o[0][0];
  const f16* qTb = qT_h + (size_t)b * D_ * QL_;
  for (int jt = 0; jt < 16; ++jt) {
    #pragma unroll
    for (int s = 0; s < 2; ++s) {
      int cidx = tid + 512 * s;          // 256 rows x 4 16B-chunks
      int row = cidx >> 2, co = cidx & 3;
      *(f16x8*)(&qT_t[row][co * 8]) =
          *(const f16x8*)(qTb + (size_t)row * QL_ + jt * 32 + co * 8);
    }
    __syncthreads();
    f16x8 p0 = *(const f16x8*)(&P_t[l15     ][jt * 32 + 8 * g]);
    f16x8 p1 = *(const f16x8*)(&P_t[16 + l15][jt * 32 + 8 * g]);
    #pragma unroll
    for (int fd = 0; fd < 2; ++fd) {
      f16x8 qb = *(const f16x8*)(&qT_t[w * 32 + 16 * fd + l15][8 * g]);
      o[0][fd] = __builtin_amdgcn_mfma_f32_16x16x32_f16(p0, qb, o[0][fd], 0, 0, 0);
      o[1][fd] = __builtin_amdgcn_mfma_f32_16x16x32_f16(p1, qb, o[1][fd], 0, 0, 0);
    }
    __syncthreads();
  }

  // ---- Epilogue: out[0:D]=c, [D:2D]=c2q, [2D:3D]=c*c2q ----
  #pragma unroll
  for (int fi = 0; fi < 2; ++fi) {
    #pragma unroll
    for (int fd = 0; fd < 2; ++fd) {
      #pragma unroll
      for (int r = 0; r < 4; ++r) {
        int il = 16 * fi + 4 * g + r;
        int d  = w * 32 + 16 * fd + l15;
        size_t rowoff = (size_t)(b * CL_ + i0 + il);
        float c2q = o[fi][fd][r] * lf[il];
        float cv  = c[rowoff * D_ + d];
        float* ob = out + rowoff * (4 * D_);
        ob[d]          = cv;
        ob[D_ + d]     = c2q;
        ob[2 * D_ + d] = cv * c2q;
      }
    }
  }
}

// ---------------- K2: bvec = softmax_i(mrow); q2c = bvec @ c -------------
__global__ __launch_bounds__(256) void k2_q2c(const float* __restrict__ c,
                                              const float* __restrict__ mrow,
                                              float* __restrict__ q2c) {
  __shared__ float bvl[CL_];
  __shared__ float redl[256];
  __shared__ f32x4 part[4][64];
  int b = blockIdx.x, tid = threadIdx.x;
  const float* mr = mrow + b * CL_;
  float mx = -1e30f;
  for (int i = tid; i < CL_; i += 256) mx = fmaxf(mx, mr[i]);
  redl[tid] = mx;
  __syncthreads();
  for (int s = 128; s > 0; s >>= 1) {
    if (tid < s) redl[tid] = fmaxf(redl[tid], redl[tid + s]);
    __syncthreads();
  }
  float gmx = redl[0];
  __syncthreads();
  float psum = 0.f;
  for (int i = tid; i < CL_; i += 256) {
    float e = __expf(mr[i] - gmx);
    bvl[i] = e;
    psum += e;
  }
  redl[tid] = psum;
  __syncthreads();
  for (int s = 128; s > 0; s >>= 1) {
    if (tid < s) redl[tid] += redl[tid + s];
    __syncthreads();
  }
  float inv = 1.0f / redl[0];
  int ro = tid >> 6, dl = tid & 63;
  f32x4 av = (f32x4){0.f,0.f,0.f,0.f};
  const float* cb = c + (size_t)b * CL_ * D_;
  for (int i = ro; i < CL_; i += 4) {
    float wgt = bvl[i];
    f32x4 v = *(const f32x4*)(cb + (size_t)i * D_ + dl * 4);
    av[0] += wgt * v[0]; av[1] += wgt * v[1];
    av[2] += wgt * v[2]; av[3] += wgt * v[3];
  }
  part[ro][dl] = av;
  __syncthreads();
  if (tid < 64) {
    f32x4 s4 = (part[0][tid] + part[1][tid]) + (part[2][tid] + part[3][tid]);
    s4[0] *= inv; s4[1] *= inv; s4[2] *= inv; s4[3] *= inv;
    *(f32x4*)(q2c + b * D_ + tid * 4) = s4;
  }
}

// ---------------- K3: out[3D:4D] = c * q2c (broadcast) -------------------
__global__ __launch_bounds__(256) void k3_tail(const float* __restrict__ c,
                                               const float* __restrict__ q2c,
                                               float* __restrict__ out) {
  size_t idx = (size_t)blockIdx.x * 256 + threadIdx.x;   // over B*CL*64 float4s
  int b   = (int)(idx >> 16);
  int rem = (int)(idx & 65535);
  int i = rem >> 6, d4 = (rem & 63) * 4;
  f32x4 cv = *(const f32x4*)(c + (size_t)(b * CL_ + i) * D_ + d4);
  f32x4 gv = *(const f32x4*)(q2c + b * D_ + d4);
  f32x4 r;
  r[0] = cv[0]*gv[0]; r[1] = cv[1]*gv[1]; r[2] = cv[2]*gv[2]; r[3] = cv[3]*gv[3];
  *(f32x4*)(out + (size_t)(b * CL_ + i) * (4 * D_) + 3 * D_ + d4) = r;
}

extern "C" void kernel_launch(void* const* d_in, const int* in_sizes, int n_in,
                              void* d_out, int out_size, void* d_ws, size_t ws_size,
                              hipStream_t stream) {
  const float* c    = (const float*)d_in[0];
  const float* q    = (const float*)d_in[1];
  const float* w_c  = (const float*)d_in[2];
  const float* w_q  = (const float*)d_in[4];
  const float* w_cq = (const float*)d_in[6];
  // biases d_in[3], d_in[5], d_in[7] provably cancel in softmaxes -> unused
  float* out = (float*)d_out;
  char* ws = (char*)d_ws;
  f16*   q_h  = (f16*)ws;                       //  8,388,608 B
  f16*   qT_h = (f16*)(ws + 8388608);           //  8,388,608 B
  float* sqv  = (float*)(ws + 16777216);        //     65,536 B
  float* mrow = (float*)(ws + 16842752);        //    131,072 B
  float* q2c  = (float*)(ws + 16973824);        //     32,768 B  (tot 17,006,592)

  hipLaunchKernelGGL(k0a_qcast,  dim3(4096),    dim3(256), 0, stream, q, w_q, q_h, sqv);
  hipLaunchKernelGGL(k0b_qtrans, dim3(8, 4, 32),dim3(256), 0, stream, q_h, qT_h);
  hipLaunchKernelGGL(k1_attn,    dim3(32, 32),  dim3(512), 0, stream,
                     c, q_h, qT_h, sqv, w_c, w_cq, out, mrow);
  hipLaunchKernelGGL(k2_q2c,     dim3(32),      dim3(256), 0, stream, c, mrow, q2c);
  hipLaunchKernelGGL(k3_tail,    dim3(8192),    dim3(256), 0, stream, c, q2c, out);
}

// Round 2
// 114.680 us; speedup vs baseline: 1.4843x; 1.4843x over previous
//
#include <hip/hip_runtime.h>

#define B_  32
#define CL_ 1024
#define QL_ 512
#define D_  256
#define BM  32

typedef _Float16 f16;
typedef __attribute__((ext_vector_type(2))) _Float16 f16x2;
typedef __attribute__((ext_vector_type(4))) _Float16 f16x4;
typedef __attribute__((ext_vector_type(8))) _Float16 f16x8;
typedef __attribute__((ext_vector_type(4))) float    f32x4;

// ------- K0: q -> f16 (q_h), qT_h transpose, sqv[b,j] = q.w_q — fused ----
__global__ __launch_bounds__(256) void k0_prep(const float* __restrict__ q,
                                               const float* __restrict__ w_q,
                                               f16* __restrict__ q_h,
                                               f16* __restrict__ qT_h,
                                               float* __restrict__ sqv) {
  __shared__ f16 q_l[64][258];                 // +2 pad: row stride 516B
  int b = blockIdx.y, j0 = blockIdx.x * 64, tid = threadIdx.x;
  int r = tid >> 2, seg = tid & 3;             // row j0+r, d-quarter seg
  const float* qrow = q   + ((size_t)(b * QL_ + j0 + r)) * D_ + seg * 64;
  f16*        qhrow = q_h + ((size_t)(b * QL_ + j0 + r)) * D_ + seg * 64;
  float dot = 0.f;
  #pragma unroll
  for (int u = 0; u < 16; ++u) {
    f32x4 v  = *(const f32x4*)(qrow + 4 * u);
    f32x4 wv = *(const f32x4*)(w_q + seg * 64 + 4 * u);
    f16x4 h;
    h[0] = (f16)v[0]; h[1] = (f16)v[1]; h[2] = (f16)v[2]; h[3] = (f16)v[3];
    *(f16x4*)(&q_l[r][seg * 64 + 4 * u]) = h;
    *(f16x4*)(qhrow + 4 * u) = h;
    dot += v[0]*wv[0] + v[1]*wv[1] + v[2]*wv[2] + v[3]*wv[3];
  }
  dot += __shfl_xor(dot, 1, 64);
  dot += __shfl_xor(dot, 2, 64);
  if (seg == 0) sqv[b * QL_ + j0 + r] = dot;
  __syncthreads();
  f16* qTb = qT_h + (size_t)b * D_ * QL_ + j0;
  #pragma unroll
  for (int s = 0; s < 32; ++s) {
    int e = tid + 256 * s;                     // 256 d x 32 j-pairs
    int d = e >> 5, j2 = (e & 31) * 2;
    f16x2 p;
    p[0] = q_l[j2][d];
    p[1] = q_l[j2 + 1][d];
    *(f16x2*)(qTb + (size_t)d * QL_ + j2) = p;
  }
}

// ---------------- K1: scores + softmax + PV + epilogue -------------------
// 512 thr = 8 waves. Phase A/C: B-operand fragments loaded DIRECTLY from
// global (L2-resident), no staging barriers. LDS 38784 B:
//   cw_t[32][264] @0 (phase A)  aliased by  P_t[32][520] @0 (phase C)
//   smalls @33280.
__global__ __launch_bounds__(512, 4) void k1_attn(
    const float* __restrict__ c, const f16* __restrict__ q_h,
    const f16* __restrict__ qT_h, const float* __restrict__ sqv,
    const float* __restrict__ w_c, const float* __restrict__ w_cq,
    float* __restrict__ out, float* __restrict__ mrow)
{
  __shared__ alignas(16) char smem[38784];
  f16 (*cw_t)[264] = (f16 (*)[264])(smem);
  f16 (*P_t)[520]  = (f16 (*)[520])(smem);
  float* sqv_l = (float*)(smem + 33280);
  float* wcq_l = (float*)(smem + 35328);
  float* wc_l  = (float*)(smem + 36352);
  float* scv_l = (float*)(smem + 37376);
  float (*red)[BM] = (float (*)[BM])(smem + 37504);
  float* mf = (float*)(smem + 38528);
  float* lf = (float*)(smem + 38656);

  const int tid = threadIdx.x;
  const int w = tid >> 6, l = tid & 63, g = l >> 4, l15 = l & 15;
  // XCD swizzle: each XCD owns 4 consecutive batches (q slice 1MB << 4MB L2)
  const int lin = blockIdx.x, xcd = lin & 7, slot = lin >> 3;
  const int b = (xcd << 2) | (slot >> 5);
  const int i0 = (slot & 31) * BM;

  if (tid < 256) { wcq_l[tid] = w_cq[tid]; wc_l[tid] = w_c[tid]; }
  sqv_l[tid] = sqv[b * QL_ + tid];
  __syncthreads();

  // stage cw_t = f16(c * w_cq); scv = c . w_c (f32)
  {
    int r = tid >> 4, seg = tid & 15;
    const float* crow = c + (size_t)(b * CL_ + i0 + r) * D_;
    float dot = 0.f;
    #pragma unroll
    for (int u = 0; u < 4; ++u) {
      int d = seg * 16 + u * 4;
      f32x4 v  = *(const f32x4*)(crow + d);
      f32x4 wv = *(const f32x4*)(wcq_l + d);
      f32x4 w2 = *(const f32x4*)(wc_l + d);
      f16x4 h;
      h[0] = (f16)(v[0]*wv[0]); h[1] = (f16)(v[1]*wv[1]);
      h[2] = (f16)(v[2]*wv[2]); h[3] = (f16)(v[3]*wv[3]);
      *(f16x4*)(&cw_t[r][d]) = h;
      dot += v[0]*w2[0] + v[1]*w2[1] + v[2]*w2[2] + v[3]*w2[3];
    }
    dot += __shfl_xor(dot, 1, 64); dot += __shfl_xor(dot, 2, 64);
    dot += __shfl_xor(dot, 4, 64); dot += __shfl_xor(dot, 8, 64);
    if (seg == 0) scv_l[r] = dot;
  }
  __syncthreads();

  // ---- Phase A: U = (c*w_cq) @ q^T; wave w owns j in [64w,64w+64) ------
  // B fragment loaded straight from global; zero barriers in this loop.
  f32x4 acc[2][4];
  #pragma unroll
  for (int fi = 0; fi < 2; ++fi)
    #pragma unroll
    for (int fj = 0; fj < 4; ++fj)
      acc[fi][fj] = (f32x4){0.f,0.f,0.f,0.f};

  const f16* qhb = q_h + (size_t)b * QL_ * D_;
  #pragma unroll
  for (int dk = 0; dk < 8; ++dk) {
    f16x8 a0 = *(const f16x8*)(&cw_t[l15     ][dk * 32 + 8 * g]);
    f16x8 a1 = *(const f16x8*)(&cw_t[16 + l15][dk * 32 + 8 * g]);
    #pragma unroll
    for (int fj = 0; fj < 4; ++fj) {
      f16x8 bf = *(const f16x8*)(qhb + (size_t)(64*w + 16*fj + l15) * D_ + dk * 32 + 8 * g);
      acc[0][fj] = __builtin_amdgcn_mfma_f32_16x16x32_f16(a0, bf, acc[0][fj], 0, 0, 0);
      acc[1][fj] = __builtin_amdgcn_mfma_f32_16x16x32_f16(a1, bf, acc[1][fj], 0, 0, 0);
    }
  }

  // ---- Phase B: softmax over j ----
  float rmax[2][4];
  #pragma unroll
  for (int fi = 0; fi < 2; ++fi) {
    #pragma unroll
    for (int r = 0; r < 4; ++r) {
      float mx = -1e30f;
      #pragma unroll
      for (int fj = 0; fj < 4; ++fj) {
        float v = acc[fi][fj][r] + sqv_l[w * 64 + 16 * fj + l15];
        acc[fi][fj][r] = v;
        mx = fmaxf(mx, v);
      }
      mx = fmaxf(mx, __shfl_xor(mx, 1, 64));
      mx = fmaxf(mx, __shfl_xor(mx, 2, 64));
      mx = fmaxf(mx, __shfl_xor(mx, 4, 64));
      mx = fmaxf(mx, __shfl_xor(mx, 8, 64));
      rmax[fi][r] = mx;
    }
  }
  if (l15 == 0) {
    #pragma unroll
    for (int fi = 0; fi < 2; ++fi)
      #pragma unroll
      for (int r = 0; r < 4; ++r)
        red[w][16 * fi + 4 * g + r] = rmax[fi][r];
  }
  __syncthreads();   // also fences all phase-A cw_t reads (P_t aliases cw_t)
  if (tid < BM) {
    float m = red[0][tid];
    #pragma unroll
    for (int w2 = 1; w2 < 8; ++w2) m = fmaxf(m, red[w2][tid]);
    mf[tid] = m;
    mrow[b * CL_ + i0 + tid] = m + scv_l[tid];
  }
  __syncthreads();

  float rsum[2][4];
  #pragma unroll
  for (int fi = 0; fi < 2; ++fi) {
    #pragma unroll
    for (int r = 0; r < 4; ++r) {
      int il = 16 * fi + 4 * g + r;
      float mv = mf[il];
      float s = 0.f;
      #pragma unroll
      for (int fj = 0; fj < 4; ++fj) {
        float p = __expf(acc[fi][fj][r] - mv);
        s += p;
        P_t[il][w * 64 + 16 * fj + l15] = (f16)p;
      }
      s += __shfl_xor(s, 1, 64); s += __shfl_xor(s, 2, 64);
      s += __shfl_xor(s, 4, 64); s += __shfl_xor(s, 8, 64);
      rsum[fi][r] = s;
    }
  }
  if (l15 == 0) {
    #pragma unroll
    for (int fi = 0; fi < 2; ++fi)
      #pragma unroll
      for (int r = 0; r < 4; ++r)
        red[w][16 * fi + 4 * g + r] = rsum[fi][r];
  }
  __syncthreads();
  if (tid < BM) {
    float s = 0.f;
    #pragma unroll
    for (int w2 = 0; w2 < 8; ++w2) s += red[w2][tid];
    lf[tid] = 1.0f / s;
  }
  __syncthreads();   // P_t fully written; phase C may read

  // ---- Phase C: O = P @ q; wave w owns d in [32w,32w+32); no barriers --
  f32x4 o[2][2];
  o[0][0] = (f32x4){0.f,0.f,0.f,0.f}; o[0][1] = o[0][0];
  o[1][0] = o[0][0];                  o[1][1] = o[0][0];
  const f16* qTb = qT_h + (size_t)b * D_ * QL_;
  #pragma unroll
  for (int jt = 0; jt < 16; ++jt) {
    f16x8 p0 = *(const f16x8*)(&P_t[l15     ][jt * 32 + 8 * g]);
    f16x8 p1 = *(const f16x8*)(&P_t[16 + l15][jt * 32 + 8 * g]);
    #pragma unroll
    for (int fd = 0; fd < 2; ++fd) {
      f16x8 qf = *(const f16x8*)(qTb + (size_t)(32*w + 16*fd + l15) * QL_ + jt * 32 + 8 * g);
      o[0][fd] = __builtin_amdgcn_mfma_f32_16x16x32_f16(p0, qf, o[0][fd], 0, 0, 0);
      o[1][fd] = __builtin_amdgcn_mfma_f32_16x16x32_f16(p1, qf, o[1][fd], 0, 0, 0);
    }
  }

  // ---- Epilogue: out[0:D]=c, [D:2D]=c2q, [2D:3D]=c*c2q (c rows L2-hot) -
  #pragma unroll
  for (int fi = 0; fi < 2; ++fi) {
    #pragma unroll
    for (int fd = 0; fd < 2; ++fd) {
      #pragma unroll
      for (int r = 0; r < 4; ++r) {
        int il = 16 * fi + 4 * g + r;
        int d  = w * 32 + 16 * fd + l15;
        size_t rowoff = (size_t)(b * CL_ + i0 + il);
        float c2q = o[fi][fd][r] * lf[il];
        float cv  = c[rowoff * D_ + d];
        float* ob = out + rowoff * (4 * D_);
        ob[d]          = cv;
        ob[D_ + d]     = c2q;
        ob[2 * D_ + d] = cv * c2q;
      }
    }
  }
}

// ------- K2a: bvec[b,:] = softmax_i(mrow[b,:]) (normalized, f32) ---------
__global__ __launch_bounds__(256) void k2a_bvec(const float* __restrict__ mrow,
                                                float* __restrict__ bvec) {
  __shared__ float red[256];
  int b = blockIdx.x, tid = threadIdx.x;
  f32x4 v = *(const f32x4*)(mrow + b * CL_ + tid * 4);
  float mx = fmaxf(fmaxf(v[0], v[1]), fmaxf(v[2], v[3]));
  red[tid] = mx;
  __syncthreads();
  for (int s = 128; s > 0; s >>= 1) {
    if (tid < s) red[tid] = fmaxf(red[tid], red[tid + s]);
    __syncthreads();
  }
  float gmx = red[0];
  __syncthreads();
  f32x4 e;
  e[0] = __expf(v[0] - gmx); e[1] = __expf(v[1] - gmx);
  e[2] = __expf(v[2] - gmx); e[3] = __expf(v[3] - gmx);
  red[tid] = e[0] + e[1] + e[2] + e[3];
  __syncthreads();
  for (int s = 128; s > 0; s >>= 1) {
    if (tid < s) red[tid] += red[tid + s];
    __syncthreads();
  }
  float inv = 1.0f / red[0];
  e[0] *= inv; e[1] *= inv; e[2] *= inv; e[3] *= inv;
  *(f32x4*)(bvec + b * CL_ + tid * 4) = e;
}

// ------- K2b: part[b,ch,:] = sum_{i in chunk} bvec[i] * c[i,:] -----------
__global__ __launch_bounds__(256) void k2b_part(const float* __restrict__ c,
                                                const float* __restrict__ bvec,
                                                float* __restrict__ part) {
  __shared__ f32x4 pl[4][64];
  int ch = blockIdx.x, b = blockIdx.y, tid = threadIdx.x;
  int ro = tid >> 6, dl = tid & 63;
  const float* cb = c + ((size_t)b * CL_ + ch * 128) * D_;
  const float* bv = bvec + b * CL_ + ch * 128;
  f32x4 acc = (f32x4){0.f, 0.f, 0.f, 0.f};
  for (int i = ro; i < 128; i += 4) {
    float wgt = bv[i];
    f32x4 v = *(const f32x4*)(cb + (size_t)i * D_ + dl * 4);
    acc[0] += wgt * v[0]; acc[1] += wgt * v[1];
    acc[2] += wgt * v[2]; acc[3] += wgt * v[3];
  }
  pl[ro][dl] = acc;
  __syncthreads();
  if (tid < 64) {
    f32x4 s = (pl[0][tid] + pl[1][tid]) + (pl[2][tid] + pl[3][tid]);
    *(f32x4*)(part + ((size_t)(b * 8 + ch)) * D_ + tid * 4) = s;
  }
}

// ------- K2c: q2c[b,:] = sum_ch part[b,ch,:] -----------------------------
__global__ __launch_bounds__(256) void k2c_red(const float* __restrict__ part,
                                               float* __restrict__ q2c) {
  int b = blockIdx.x, d = threadIdx.x;
  float s = 0.f;
  #pragma unroll
  for (int ch = 0; ch < 8; ++ch) s += part[((size_t)(b * 8 + ch)) * D_ + d];
  q2c[b * D_ + d] = s;
}

// ------- K3: out[3D:4D] = c * q2c (broadcast) ----------------------------
__global__ __launch_bounds__(256) void k3_tail(const float* __restrict__ c,
                                               const float* __restrict__ q2c,
                                               float* __restrict__ out) {
  size_t idx = (size_t)blockIdx.x * 256 + threadIdx.x;   // B*CL*64 float4s
  int b   = (int)(idx >> 16);
  int rem = (int)(idx & 65535);
  int i = rem >> 6, d4 = (rem & 63) * 4;
  f32x4 cv = *(const f32x4*)(c + (size_t)(b * CL_ + i) * D_ + d4);
  f32x4 gv = *(const f32x4*)(q2c + b * D_ + d4);
  f32x4 r;
  r[0] = cv[0]*gv[0]; r[1] = cv[1]*gv[1]; r[2] = cv[2]*gv[2]; r[3] = cv[3]*gv[3];
  *(f32x4*)(out + (size_t)(b * CL_ + i) * (4 * D_) + 3 * D_ + d4) = r;
}

extern "C" void kernel_launch(void* const* d_in, const int* in_sizes, int n_in,
                              void* d_out, int out_size, void* d_ws, size_t ws_size,
                              hipStream_t stream) {
  const float* c    = (const float*)d_in[0];
  const float* q    = (const float*)d_in[1];
  const float* w_c  = (const float*)d_in[2];
  const float* w_q  = (const float*)d_in[4];
  const float* w_cq = (const float*)d_in[6];
  // biases d_in[3], d_in[5], d_in[7] cancel in both softmaxes -> unused
  float* out = (float*)d_out;
  char* ws = (char*)d_ws;
  f16*   q_h  = (f16*)ws;                       //  8,388,608 B
  f16*   qT_h = (f16*)(ws + 8388608);           //  8,388,608 B
  float* sqv  = (float*)(ws + 16777216);        //     65,536 B
  float* mrow = (float*)(ws + 16842752);        //    131,072 B
  float* bvec = (float*)(ws + 16973824);        //    131,072 B
  float* part = (float*)(ws + 17104896);        //    262,144 B
  float* q2c  = (float*)(ws + 17367040);        //     32,768 B (tot 17,399,808)

  hipLaunchKernelGGL(k0_prep,  dim3(8, 32),  dim3(256), 0, stream, q, w_q, q_h, qT_h, sqv);
  hipLaunchKernelGGL(k1_attn,  dim3(1024),   dim3(512), 0, stream,
                     c, q_h, qT_h, sqv, w_c, w_cq, out, mrow);
  hipLaunchKernelGGL(k2a_bvec, dim3(32),     dim3(256), 0, stream, mrow, bvec);
  hipLaunchKernelGGL(k2b_part, dim3(8, 32),  dim3(256), 0, stream, c, bvec, part);
  hipLaunchKernelGGL(k2c_red,  dim3(32),     dim3(256), 0, stream, part, q2c);
  hipLaunchKernelGGL(k3_tail,  dim3(8192),   dim3(256), 0, stream, c, q2c, out);
}